// Round 15
// baseline (216.965 us; speedup 1.0000x reference)
//
#include <hip/hip_runtime.h>

#define NC 2048
#define D 64
#define H 32

typedef __fp16 h2 __attribute__((ext_vector_type(2)));
typedef unsigned int u32;

#if __has_builtin(__builtin_amdgcn_fdot2)
#define FDOT2(a, b, c) __builtin_amdgcn_fdot2((a), (b), (c), false)
#else
#define FDOT2(a, b, c) ((c) + (float)(a)[0] * (float)(b)[0] + (float)(a)[1] * (float)(b)[1])
#endif
#define BC2(u) __builtin_bit_cast(h2, (u))

// ---------------- K1: segment bounds (owner sorted ascending) -------------
__global__ void bounds_kernel(const int* __restrict__ owner,
                              int* __restrict__ bounds, int n) {
    int i = blockIdx.x * blockDim.x + threadIdx.x;
    if (i >= n) return;
    int o  = owner[i];
    int op = (i == 0) ? -1 : owner[i - 1];
    for (int g = op + 1; g <= o; ++g) bounds[g] = i;
    if (i == n - 1)
        for (int g = o + 1; g <= NC; ++g) bounds[g] = n;
}

// ---------------- K2: per-crystal kernel, lane = (head, ALL dims) ---------
// R14 lesson: permlane32_swap semantics unverifiable -> reverted. R13 residual
// stall theory: per-atom cross-lane (shfl -> DS op) drains lgkmcnt, which also
// drains the next atom's prefetched ds_reads -> pipeline serialized per atom.
// R15 removes ALL per-atom cross-lane STRUCTURALLY: lane owns (head h, all 64
// dims); the two 32-lane halves of a wave process even/odd atoms of the
// wave's contiguous slice. Per atom-pair: each half broadcasts-reads its own
// atom's full fp16 row (8 ds_read_b128/pair = 4/atom, same as R13), 32 FDOT2
// full dot per lane -> logit complete IN-LANE, exp (1/pair, half of R13),
// 64 outer FMAs into acc[64]. Per-lane es sums its own atoms' p.
// Combine: once per wave at the end, LDS atomicAdd (ds_add_f32) into shared
// accbuf[64][32] + esum[32]; readout divides. Zero per-atom sync of any kind.
// fp16 staging identical to R12/R13 (verified, absmax 0.0156).
// Occupancy law (R4-R9): VGPR cap = 512/(LDS-implied waves/EU). Demand ~148
// (acc64+wkh32+xx32+misc) -> pad LDS to ~41KB -> 3 blocks/CU (256 thr) ->
// 3 waves/EU -> cap 170. 12 waves/CU suffices for a stall-free FMA stream.
__global__ __launch_bounds__(256)
void crystal_kernel(
    const float* __restrict__ atom_feas,
    const float* __restrict__ Wk,
    const float* __restrict__ bk,
    const int* __restrict__ bounds,
    float* __restrict__ out,
    int n)
{
    __shared__ __align__(16) u32 stage[4][2][8][32];   // 8 KB fp16 staging
    __shared__ float accbuf[D * H];                    // 8 KB combine buffer
    __shared__ float esum[H];
    __shared__ float lds_pad[6200];                    // 24.8 KB occupancy shaper

    const int g    = blockIdx.x;
    const int tid  = threadIdx.x;
    const int lane = tid & 63;
    const int wv   = tid >> 6;          // 0..3
    const int h    = lane & 31;         // head owned by this lane
    const int hf   = lane >> 5;         // 0: even atoms, 1: odd atoms

    // zero the combine buffers
    #pragma unroll
    for (int k = 0; k < 8; ++k) accbuf[tid + k * 256] = 0.f;
    if (tid < H) esum[tid] = 0.f;

    // full Wk column h as packed half2 (32 regs)
    h2 wkh[32];
    #pragma unroll
    for (int j = 0; j < 32; ++j)
        wkh[j] = __builtin_amdgcn_cvt_pkrtz(Wk[(2 * j) * H + h],
                                            Wk[(2 * j + 1) * H + h]);
    const float bkv = bk[h];

    const int s   = bounds[g];
    const int e   = bounds[g + 1];
    const int per = (e - s + 3) >> 2;   // contiguous slice per wave
    const int a0  = s + wv * per;
    const int ae  = min(a0 + per, e);

    float acc[64];
    #pragma unroll
    for (int j = 0; j < 64; ++j) acc[j] = 0.f;
    float es = 0.f;

    __syncthreads();   // accbuf/esum zero-init visible before any end-adds

    if (a0 < ae) {
        const int nchunk = (ae - a0 + 7) >> 3;
        const int maxf4  = n * 16 - 1;            // clamp staging reads in-bounds
        const float4* af4 = (const float4*)atom_feas;

        int cb = a0;                               // prologue: chunk 0 -> regs
        float4 r0 = af4[min(cb * 16 + lane,      maxf4)];
        float4 r1 = af4[min(cb * 16 + lane + 64, maxf4)];

        for (int c = 0; c < nchunk; ++c) {
            {   // pack chunk c to fp16, write to wave-private LDS buffer
                uint2* sw = (uint2*)stage[wv][c & 1];
                const h2 p0 = __builtin_amdgcn_cvt_pkrtz(r0.x, r0.y);
                const h2 p1 = __builtin_amdgcn_cvt_pkrtz(r0.z, r0.w);
                const h2 p2 = __builtin_amdgcn_cvt_pkrtz(r1.x, r1.y);
                const h2 p3 = __builtin_amdgcn_cvt_pkrtz(r1.z, r1.w);
                uint2 w0, w1;
                w0.x = __builtin_bit_cast(u32, p0); w0.y = __builtin_bit_cast(u32, p1);
                w1.x = __builtin_bit_cast(u32, p2); w1.y = __builtin_bit_cast(u32, p3);
                const int slot = lane & 15, arow = lane >> 4;
                sw[arow * 16 + slot]       = w0;   // atoms 0..3 of chunk
                sw[(arow + 4) * 16 + slot] = w1;   // atoms 4..7
            }
            const int nb = cb + 8;
            if (c + 1 < nchunk) {                  // issue chunk c+1 loads now;
                r0 = af4[min(nb * 16 + lane,      maxf4)];  // fly during compute
                r1 = af4[min(nb * 16 + lane + 64, maxf4)];
            }

            const uint4* srbase = (const uint4*)stage[wv][c & 1];
            #pragma unroll
            for (int i = 0; i < 4; ++i) {          // 4 atom-pairs per chunk
                const int aa = cb + 2 * i + hf;    // this half's atom
                const uint4* sr = srbase + (2 * i + hf) * 8;
                uint4 xx[8];
                #pragma unroll
                for (int j = 0; j < 8; ++j) xx[j] = sr[j];

                float q0 = 0.f, q1 = 0.f, q2 = 0.f, q3 = 0.f;
                #pragma unroll
                for (int j = 0; j < 8; ++j) {
                    q0 = FDOT2(BC2(xx[j].x), wkh[4 * j + 0], q0);
                    q1 = FDOT2(BC2(xx[j].y), wkh[4 * j + 1], q1);
                    q2 = FDOT2(BC2(xx[j].z), wkh[4 * j + 2], q2);
                    q3 = FDOT2(BC2(xx[j].w), wkh[4 * j + 3], q3);
                }
                const float wl = (q0 + q1) + (q2 + q3) + bkv;
                const float p  = (aa < ae) ? __expf(wl) : 0.f;  // mask tail
                es += p;

                #pragma unroll
                for (int j = 0; j < 8; ++j) {
                    const h2 ha = BC2(xx[j].x);
                    const h2 hb = BC2(xx[j].y);
                    const h2 hc = BC2(xx[j].z);
                    const h2 hd = BC2(xx[j].w);
                    acc[8 * j + 0] += (float)ha[0] * p;
                    acc[8 * j + 1] += (float)ha[1] * p;
                    acc[8 * j + 2] += (float)hb[0] * p;
                    acc[8 * j + 3] += (float)hb[1] * p;
                    acc[8 * j + 4] += (float)hc[0] * p;
                    acc[8 * j + 5] += (float)hc[1] * p;
                    acc[8 * j + 6] += (float)hd[0] * p;
                    acc[8 * j + 7] += (float)hd[1] * p;
                }
            }
            cb = nb;
        }
    }

    // keep lds_pad allocated (runtime-false guard the compiler can't fold)
    if (e < s) lds_pad[tid] = es;

    // ---- combine: ds_add_f32 into shared buffers (once per wave)
    #pragma unroll
    for (int d = 0; d < 64; ++d) atomicAdd(&accbuf[d * H + h], acc[d]);
    atomicAdd(&esum[h], es);
    __syncthreads();

    // ---- readout: 256 threads x 8 outputs, coalesced
    float* og = out + (size_t)g * (D * H);
    #pragma unroll
    for (int k = 0; k < 8; ++k) {
        const int f = tid + k * 256;
        const float den = esum[f & 31];
        og[f] = (den > 0.f) ? accbuf[f] / den : 0.f;
    }
}

// ---------------- Fallback (ws too small): known-good fused kernel --------
#define CHUNK 64
__global__ __launch_bounds__(256) void fused_kernel(
    const float* __restrict__ atom_feas,
    const float* __restrict__ Wk,
    const float* __restrict__ bk,
    const int* __restrict__ owner,
    float* __restrict__ out,
    int n_atoms)
{
    __shared__ float fea_lds[CHUNK * D];
    __shared__ float w_lds[CHUNK * H];
    __shared__ float wk_lds[D * H];
    __shared__ float bk_lds[H];

    const int g   = blockIdx.x;
    const int tid = threadIdx.x;
    const int h   = tid & 31;
    const int grp = tid >> 5;

    for (int i = tid; i < D * H; i += 256) wk_lds[i] = Wk[i];
    if (tid < H) bk_lds[tid] = bk[tid];

    int lo = 0, hi = n_atoms;
    while (lo < hi) { int mid = (lo + hi) >> 1; if (owner[mid] < g) lo = mid + 1; else hi = mid; }
    const int seg_start = lo;
    hi = n_atoms;
    while (lo < hi) { int mid = (lo + hi) >> 1; if (owner[mid] < g + 1) lo = mid + 1; else hi = mid; }
    const int seg_end = lo;

    float acc[8];
    #pragma unroll
    for (int j = 0; j < 8; ++j) acc[j] = 0.f;
    float ps = 0.f;

    __syncthreads();

    for (int base = seg_start; base < seg_end; base += CHUNK) {
        const int na = min(CHUNK, seg_end - base);
        {
            const int nf4 = na * (D / 4);
            const float4* src = (const float4*)(atom_feas + (size_t)base * D);
            float4* dst = (float4*)fea_lds;
            for (int i = tid; i < nf4; i += 256) dst[i] = src[i];
        }
        __syncthreads();

        for (int pi = tid; pi < na * H; pi += 256) {
            const int aa = pi >> 5;
            const int hh = pi & 31;
            const float* fr = fea_lds + aa * D;
            float wvl = bk_lds[hh];
            #pragma unroll
            for (int k = 0; k < D; k += 4) {
                float4 f = *(const float4*)(fr + k);
                wvl += f.x * wk_lds[(k + 0) * H + hh];
                wvl += f.y * wk_lds[(k + 1) * H + hh];
                wvl += f.z * wk_lds[(k + 2) * H + hh];
                wvl += f.w * wk_lds[(k + 3) * H + hh];
            }
            w_lds[pi] = __expf(wvl);
        }
        __syncthreads();

        for (int aa = 0; aa < na; ++aa) {
            const float p = w_lds[aa * H + h];
            ps += p;
            const float* f = fea_lds + aa * D + grp * 8;
            #pragma unroll
            for (int j = 0; j < 8; ++j) acc[j] += f[j] * p;
        }
        __syncthreads();
    }

    const float inv = (ps > 0.f) ? 1.0f / ps : 0.f;
    float* og = out + (size_t)g * (D * H);
    #pragma unroll
    for (int j = 0; j < 8; ++j) og[(grp * 8 + j) * H + h] = acc[j] * inv;
}

extern "C" void kernel_launch(void* const* d_in, const int* in_sizes, int n_in,
                              void* d_out, int out_size, void* d_ws, size_t ws_size,
                              hipStream_t stream) {
    const float* atom_feas = (const float*)d_in[0];
    const float* Wk        = (const float*)d_in[1];
    const float* bk        = (const float*)d_in[2];
    // d_in[3] = atomic_numbers (unused by the reference)
    const int*   owner     = (const int*)d_in[4];
    const int n_atoms = in_sizes[4];
    float* out = (float*)d_out;

    if (ws_size >= (NC + 1) * sizeof(int)) {
        int* bounds = (int*)d_ws;
        bounds_kernel<<<(n_atoms + 255) / 256, 256, 0, stream>>>(owner, bounds, n_atoms);
        crystal_kernel<<<NC, 256, 0, stream>>>(atom_feas, Wk, bk, bounds, out, n_atoms);
    } else {
        fused_kernel<<<NC, 256, 0, stream>>>(atom_feas, Wk, bk, owner, out, n_atoms);
    }
}

// Round 16
// 57.905 us; speedup vs baseline: 3.7469x; 3.7469x over previous
//
#include <hip/hip_runtime.h>

#define NC 2048
#define D 64
#define H 32

typedef __fp16 h2 __attribute__((ext_vector_type(2)));
typedef unsigned int u32;

#if __has_builtin(__builtin_amdgcn_fdot2)
#define FDOT2(a, b, c) __builtin_amdgcn_fdot2((a), (b), (c), false)
#else
#define FDOT2(a, b, c) ((c) + (float)(a)[0] * (float)(b)[0] + (float)(a)[1] * (float)(b)[1])
#endif
#define BC2(u) __builtin_bit_cast(h2, (u))

// ---------------- K1: segment bounds (owner sorted ascending) -------------
__global__ void bounds_kernel(const int* __restrict__ owner,
                              int* __restrict__ bounds, int n) {
    int i = blockIdx.x * blockDim.x + threadIdx.x;
    if (i >= n) return;
    int o  = owner[i];
    int op = (i == 0) ? -1 : owner[i - 1];
    for (int g = op + 1; g <= o; ++g) bounds[g] = i;
    if (i == n - 1)
        for (int g = o + 1; g <= NC; ++g) bounds[g] = n;
}

// ---------------- K2: per-crystal kernel, lane = (head, ALL dims) ---------
// R15 post-mortem: core loop correct & zero per-atom cross-lane, but the
// ending combine used 64 ds_add_f32 atomics/lane -> DS-pipe serialization
// (~130k DS-cy/CU) = the whole 217us (VALU 9%, HBM 1%). R16 keeps the R15
// core verbatim and replaces ONLY the combine:
//   1) once-per-kernel intra-wave fold: acc[d] += shfl_xor(acc[d],32) (65 ops)
//   2) lanes<32 of each wave write part[wv][d][lane] (real array, 34.3KB --
//      R15 lesson: fake lds_pad gets DCE'd; only REAL arrays shape occupancy)
//   3) one barrier; 256 threads x 8 coalesced outputs, sum 4 partials, divide.
// Occupancy law (R4-R9): LDS 41.5KB -> 3 blocks/CU -> 3 waves/EU -> VGPR cap
// 170 >= demand (~150, R15 fit in 132 without spill). part col 33 -> 2-way max.
__global__ __launch_bounds__(256)
void crystal_kernel(
    const float* __restrict__ atom_feas,
    const float* __restrict__ Wk,
    const float* __restrict__ bk,
    const int* __restrict__ bounds,
    float* __restrict__ out,
    int n)
{
    __shared__ __align__(16) u32 stage[4][2][8][32];   // 8 KB fp16 staging
    __shared__ float part[4][65][33];                  // 34.3 KB wave partials

    const int g    = blockIdx.x;
    const int tid  = threadIdx.x;
    const int lane = tid & 63;
    const int wv   = tid >> 6;          // 0..3
    const int h    = lane & 31;         // head owned by this lane
    const int hf   = lane >> 5;         // 0: even atoms, 1: odd atoms

    // full Wk column h as packed half2 (32 regs)
    h2 wkh[32];
    #pragma unroll
    for (int j = 0; j < 32; ++j)
        wkh[j] = __builtin_amdgcn_cvt_pkrtz(Wk[(2 * j) * H + h],
                                            Wk[(2 * j + 1) * H + h]);
    const float bkv = bk[h];

    const int s   = bounds[g];
    const int e   = bounds[g + 1];
    const int per = (e - s + 3) >> 2;   // contiguous slice per wave
    const int a0  = s + wv * per;
    const int ae  = min(a0 + per, e);

    float acc[64];
    #pragma unroll
    for (int j = 0; j < 64; ++j) acc[j] = 0.f;
    float es = 0.f;

    if (a0 < ae) {
        const int nchunk = (ae - a0 + 7) >> 3;
        const int maxf4  = n * 16 - 1;            // clamp staging reads in-bounds
        const float4* af4 = (const float4*)atom_feas;

        int cb = a0;                               // prologue: chunk 0 -> regs
        float4 r0 = af4[min(cb * 16 + lane,      maxf4)];
        float4 r1 = af4[min(cb * 16 + lane + 64, maxf4)];

        for (int c = 0; c < nchunk; ++c) {
            {   // pack chunk c to fp16, write to wave-private LDS buffer
                uint2* sw = (uint2*)stage[wv][c & 1];
                const h2 p0 = __builtin_amdgcn_cvt_pkrtz(r0.x, r0.y);
                const h2 p1 = __builtin_amdgcn_cvt_pkrtz(r0.z, r0.w);
                const h2 p2 = __builtin_amdgcn_cvt_pkrtz(r1.x, r1.y);
                const h2 p3 = __builtin_amdgcn_cvt_pkrtz(r1.z, r1.w);
                uint2 w0, w1;
                w0.x = __builtin_bit_cast(u32, p0); w0.y = __builtin_bit_cast(u32, p1);
                w1.x = __builtin_bit_cast(u32, p2); w1.y = __builtin_bit_cast(u32, p3);
                const int slot = lane & 15, arow = lane >> 4;
                sw[arow * 16 + slot]       = w0;   // atoms 0..3 of chunk
                sw[(arow + 4) * 16 + slot] = w1;   // atoms 4..7
            }
            const int nb = cb + 8;
            if (c + 1 < nchunk) {                  // issue chunk c+1 loads now;
                r0 = af4[min(nb * 16 + lane,      maxf4)];  // fly during compute
                r1 = af4[min(nb * 16 + lane + 64, maxf4)];
            }

            const uint4* srbase = (const uint4*)stage[wv][c & 1];
            #pragma unroll
            for (int i = 0; i < 4; ++i) {          // 4 atom-pairs per chunk
                const int aa = cb + 2 * i + hf;    // this half's atom
                const uint4* sr = srbase + (2 * i + hf) * 8;
                uint4 xx[8];
                #pragma unroll
                for (int j = 0; j < 8; ++j) xx[j] = sr[j];

                float q0 = 0.f, q1 = 0.f, q2 = 0.f, q3 = 0.f;
                #pragma unroll
                for (int j = 0; j < 8; ++j) {
                    q0 = FDOT2(BC2(xx[j].x), wkh[4 * j + 0], q0);
                    q1 = FDOT2(BC2(xx[j].y), wkh[4 * j + 1], q1);
                    q2 = FDOT2(BC2(xx[j].z), wkh[4 * j + 2], q2);
                    q3 = FDOT2(BC2(xx[j].w), wkh[4 * j + 3], q3);
                }
                const float wl = (q0 + q1) + (q2 + q3) + bkv;
                const float p  = (aa < ae) ? __expf(wl) : 0.f;  // mask tail
                es += p;

                #pragma unroll
                for (int j = 0; j < 8; ++j) {
                    const h2 ha = BC2(xx[j].x);
                    const h2 hb = BC2(xx[j].y);
                    const h2 hc = BC2(xx[j].z);
                    const h2 hd = BC2(xx[j].w);
                    acc[8 * j + 0] += (float)ha[0] * p;
                    acc[8 * j + 1] += (float)ha[1] * p;
                    acc[8 * j + 2] += (float)hb[0] * p;
                    acc[8 * j + 3] += (float)hb[1] * p;
                    acc[8 * j + 4] += (float)hc[0] * p;
                    acc[8 * j + 5] += (float)hc[1] * p;
                    acc[8 * j + 6] += (float)hd[0] * p;
                    acc[8 * j + 7] += (float)hd[1] * p;
                }
            }
            cb = nb;
        }
    }

    // ---- intra-wave even/odd fold (once per kernel; DS-swizzle is fine here)
    #pragma unroll
    for (int d = 0; d < 64; ++d) acc[d] += __shfl_xor(acc[d], 32, 64);
    es += __shfl_xor(es, 32, 64);

    // ---- per-wave partials to LDS (lanes 0..31 hold full-wave totals)
    if (lane < 32) {
        #pragma unroll
        for (int d = 0; d < 64; ++d) part[wv][d][lane] = acc[d];
        part[wv][64][lane] = es;
    }
    __syncthreads();

    // ---- final: 256 threads x 8 outputs, coalesced
    float* og = out + (size_t)g * (D * H);
    const int hh = tid & 31;
    const float den = part[0][64][hh] + part[1][64][hh]
                    + part[2][64][hh] + part[3][64][hh];
    const float inv = (den > 0.f) ? 1.0f / den : 0.f;
    #pragma unroll
    for (int k = 0; k < 8; ++k) {
        const int f = tid + k * 256;
        const int d = f >> 5;
        og[f] = (part[0][d][hh] + part[1][d][hh]
               + part[2][d][hh] + part[3][d][hh]) * inv;
    }
}

// ---------------- Fallback (ws too small): known-good fused kernel --------
#define CHUNK 64
__global__ __launch_bounds__(256) void fused_kernel(
    const float* __restrict__ atom_feas,
    const float* __restrict__ Wk,
    const float* __restrict__ bk,
    const int* __restrict__ owner,
    float* __restrict__ out,
    int n_atoms)
{
    __shared__ float fea_lds[CHUNK * D];
    __shared__ float w_lds[CHUNK * H];
    __shared__ float wk_lds[D * H];
    __shared__ float bk_lds[H];

    const int g   = blockIdx.x;
    const int tid = threadIdx.x;
    const int h   = tid & 31;
    const int grp = tid >> 5;

    for (int i = tid; i < D * H; i += 256) wk_lds[i] = Wk[i];
    if (tid < H) bk_lds[tid] = bk[tid];

    int lo = 0, hi = n_atoms;
    while (lo < hi) { int mid = (lo + hi) >> 1; if (owner[mid] < g) lo = mid + 1; else hi = mid; }
    const int seg_start = lo;
    hi = n_atoms;
    while (lo < hi) { int mid = (lo + hi) >> 1; if (owner[mid] < g + 1) lo = mid + 1; else hi = mid; }
    const int seg_end = lo;

    float acc[8];
    #pragma unroll
    for (int j = 0; j < 8; ++j) acc[j] = 0.f;
    float ps = 0.f;

    __syncthreads();

    for (int base = seg_start; base < seg_end; base += CHUNK) {
        const int na = min(CHUNK, seg_end - base);
        {
            const int nf4 = na * (D / 4);
            const float4* src = (const float4*)(atom_feas + (size_t)base * D);
            float4* dst = (float4*)fea_lds;
            for (int i = tid; i < nf4; i += 256) dst[i] = src[i];
        }
        __syncthreads();

        for (int pi = tid; pi < na * H; pi += 256) {
            const int aa = pi >> 5;
            const int hh = pi & 31;
            const float* fr = fea_lds + aa * D;
            float wvl = bk_lds[hh];
            #pragma unroll
            for (int k = 0; k < D; k += 4) {
                float4 f = *(const float4*)(fr + k);
                wvl += f.x * wk_lds[(k + 0) * H + hh];
                wvl += f.y * wk_lds[(k + 1) * H + hh];
                wvl += f.z * wk_lds[(k + 2) * H + hh];
                wvl += f.w * wk_lds[(k + 3) * H + hh];
            }
            w_lds[pi] = __expf(wvl);
        }
        __syncthreads();

        for (int aa = 0; aa < na; ++aa) {
            const float p = w_lds[aa * H + h];
            ps += p;
            const float* f = fea_lds + aa * D + grp * 8;
            #pragma unroll
            for (int j = 0; j < 8; ++j) acc[j] += f[j] * p;
        }
        __syncthreads();
    }

    const float inv = (ps > 0.f) ? 1.0f / ps : 0.f;
    float* og = out + (size_t)g * (D * H);
    #pragma unroll
    for (int j = 0; j < 8; ++j) og[(grp * 8 + j) * H + h] = acc[j] * inv;
}

extern "C" void kernel_launch(void* const* d_in, const int* in_sizes, int n_in,
                              void* d_out, int out_size, void* d_ws, size_t ws_size,
                              hipStream_t stream) {
    const float* atom_feas = (const float*)d_in[0];
    const float* Wk        = (const float*)d_in[1];
    const float* bk        = (const float*)d_in[2];
    // d_in[3] = atomic_numbers (unused by the reference)
    const int*   owner     = (const int*)d_in[4];
    const int n_atoms = in_sizes[4];
    float* out = (float*)d_out;

    if (ws_size >= (NC + 1) * sizeof(int)) {
        int* bounds = (int*)d_ws;
        bounds_kernel<<<(n_atoms + 255) / 256, 256, 0, stream>>>(owner, bounds, n_atoms);
        crystal_kernel<<<NC, 256, 0, stream>>>(atom_feas, Wk, bk, bounds, out, n_atoms);
    } else {
        fused_kernel<<<NC, 256, 0, stream>>>(atom_feas, Wk, bk, owner, out, n_atoms);
    }
}

// Round 17
// 39.058 us; speedup vs baseline: 5.5549x; 1.4825x over previous
//
#include <hip/hip_runtime.h>

#define NC 2048
#define D 64
#define H 32

typedef __fp16 h2 __attribute__((ext_vector_type(2)));
typedef unsigned int u32;

#if __has_builtin(__builtin_amdgcn_fdot2)
#define FDOT2(a, b, c) __builtin_amdgcn_fdot2((a), (b), (c), false)
#else
#define FDOT2(a, b, c) ((c) + (float)(a)[0] * (float)(b)[0] + (float)(a)[1] * (float)(b)[1])
#endif
#define BC2(u) __builtin_bit_cast(h2, (u))

// ---- K1: fused fp16-convert (fea -> d_ws) + segment bounds ---------------
// Elementwise: thread t converts one float4 -> uint2 (4 fp16, RTZ pack, same
// orientation verified in R12-R16: u32 k holds dims (2k,2k+1)).
// Threads with t < n also detect owner boundaries (proven R2 pattern).
__global__ __launch_bounds__(256) void convert_bounds_kernel(
    const float* __restrict__ atom_feas,
    const int* __restrict__ owner,
    uint2* __restrict__ f16fea,
    int* __restrict__ bounds,
    int n)
{
    const int t = blockIdx.x * 256 + threadIdx.x;
    const int nf4 = n * (D / 4);
    if (t < nf4) {
        const float4 v = ((const float4*)atom_feas)[t];
        uint2 w;
        w.x = __builtin_bit_cast(u32, __builtin_amdgcn_cvt_pkrtz(v.x, v.y));
        w.y = __builtin_bit_cast(u32, __builtin_amdgcn_cvt_pkrtz(v.z, v.w));
        f16fea[t] = w;
    }
    if (t < n) {
        const int o  = owner[t];
        const int op = (t == 0) ? -1 : owner[t - 1];
        for (int g = op + 1; g <= o; ++g) bounds[g] = t;
        if (t == n - 1)
            for (int g = o + 1; g <= NC; ++g) bounds[g] = n;
    }
}

// ---- K2: one WAVE per crystal, zero-DS/zero-cross-lane main loop ---------
// R16 post-mortem: every LDS-staged variant pays ~48 DS-cy/atom on the
// CU-shared DS pipe (~8us/CU floor) + only 2-3 waves/SIMD. R17: 2048
// single-wave blocks (ALL resident: 8 blocks/CU), R15-verified in-lane core
// (lane = head h, lane-halves = even/odd atoms), atom rows read DIRECTLY
// from the fp16 copy in global: 8 uniform dwordx4 per atom-pair (2 addrs per
// instr, one per half) served from L2 (12.8MB/8XCD = 1.6MB, L2-fit, freshly
// written by K1). NO ds ops, NO shuffles, NO barriers in the loop.
// Epilogue (once): 65 shfl_xor fold -> LDS transpose -> coalesced stores.
// Occupancy law (R4-R16): VGPR cap = 512/(LDS-implied waves/EU). trans[65][76]
// = 19.76KB REAL storage -> floor(160/19.76) = 8 blocks/CU -> 2 waves/SIMD ->
// cap 256 >= demand ~180 -> no spill. (R15 lesson: only real arrays count.)
__global__ __launch_bounds__(64)
void crystal_kernel(
    const uint4* __restrict__ f16row,   // fp16 fea, 8 uint4 per atom row
    const float* __restrict__ Wk,
    const float* __restrict__ bk,
    const int* __restrict__ bounds,
    float* __restrict__ out)
{
    __shared__ float trans[65][76];     // 19.76 KB: transpose buf + occupancy shaper

    const int g    = blockIdx.x;
    const int lane = threadIdx.x & 63;
    const int h    = lane & 31;         // head owned by this lane
    const int hf   = lane >> 5;         // 0: even atoms, 1: odd atoms

    // full Wk column h as packed half2 (32 regs); 8KB matrix -> L1/L2-hot
    h2 wkh[32];
    #pragma unroll
    for (int j = 0; j < 32; ++j)
        wkh[j] = __builtin_amdgcn_cvt_pkrtz(Wk[(2 * j) * H + h],
                                            Wk[(2 * j + 1) * H + h]);
    const float bkv = bk[h];

    const int s = bounds[g];
    const int e = bounds[g + 1];

    float acc[64];
    #pragma unroll
    for (int j = 0; j < 64; ++j) acc[j] = 0.f;
    float es = 0.f;

    // main loop: one atom-pair per iteration; this lane-half's atom = ab+hf
    #pragma unroll 2
    for (int ab = s; ab < e; ab += 2) {
        const int aa = ab + hf;
        const uint4* rp = f16row + (size_t)min(aa, e - 1) * 8;  // clamp odd tail
        uint4 xx[8];
        #pragma unroll
        for (int j = 0; j < 8; ++j) xx[j] = rp[j];

        float q0 = 0.f, q1 = 0.f, q2 = 0.f, q3 = 0.f;
        #pragma unroll
        for (int j = 0; j < 8; ++j) {
            q0 = FDOT2(BC2(xx[j].x), wkh[4 * j + 0], q0);
            q1 = FDOT2(BC2(xx[j].y), wkh[4 * j + 1], q1);
            q2 = FDOT2(BC2(xx[j].z), wkh[4 * j + 2], q2);
            q3 = FDOT2(BC2(xx[j].w), wkh[4 * j + 3], q3);
        }
        const float wl = (q0 + q1) + (q2 + q3) + bkv;
        const float p  = (aa < e) ? __expf(wl) : 0.f;   // mask odd tail
        es += p;

        #pragma unroll
        for (int j = 0; j < 8; ++j) {
            const h2 ha = BC2(xx[j].x);
            const h2 hb = BC2(xx[j].y);
            const h2 hc = BC2(xx[j].z);
            const h2 hd = BC2(xx[j].w);
            acc[8 * j + 0] += (float)ha[0] * p;
            acc[8 * j + 1] += (float)ha[1] * p;
            acc[8 * j + 2] += (float)hb[0] * p;
            acc[8 * j + 3] += (float)hb[1] * p;
            acc[8 * j + 4] += (float)hc[0] * p;
            acc[8 * j + 5] += (float)hc[1] * p;
            acc[8 * j + 6] += (float)hd[0] * p;
            acc[8 * j + 7] += (float)hd[1] * p;
        }
    }

    // ---- once-per-wave fold: even-half + odd-half
    #pragma unroll
    for (int d = 0; d < 64; ++d) acc[d] += __shfl_xor(acc[d], 32, 64);
    es += __shfl_xor(es, 32, 64);

    // ---- transpose via LDS for coalesced stores (single wave: barrier ~free)
    if (lane < 32) {
        #pragma unroll
        for (int d = 0; d < 64; ++d) trans[d][lane] = acc[d];
        trans[64][lane] = es;
    }
    __syncthreads();

    const float den = trans[64][h];
    const float inv = (den > 0.f) ? 1.0f / den : 0.f;
    float* og = out + (size_t)g * (D * H);
    #pragma unroll
    for (int k = 0; k < 32; ++k) {
        // f = lane + 64k: row = hf + 2k, col = h; lanes<32 read row 2k,
        // lanes>=32 row 2k+1 -> 2x32 consecutive floats, conflict-free
        og[lane + 64 * k] = trans[hf + 2 * k][h] * inv;
    }
}

// ---- Fallback (ws too small): known-good fused kernel --------------------
#define CHUNK 64
__global__ __launch_bounds__(256) void fused_kernel(
    const float* __restrict__ atom_feas,
    const float* __restrict__ Wk,
    const float* __restrict__ bk,
    const int* __restrict__ owner,
    float* __restrict__ out,
    int n_atoms)
{
    __shared__ float fea_lds[CHUNK * D];
    __shared__ float w_lds[CHUNK * H];
    __shared__ float wk_lds[D * H];
    __shared__ float bk_lds[H];

    const int g   = blockIdx.x;
    const int tid = threadIdx.x;
    const int h   = tid & 31;
    const int grp = tid >> 5;

    for (int i = tid; i < D * H; i += 256) wk_lds[i] = Wk[i];
    if (tid < H) bk_lds[tid] = bk[tid];

    int lo = 0, hi = n_atoms;
    while (lo < hi) { int mid = (lo + hi) >> 1; if (owner[mid] < g) lo = mid + 1; else hi = mid; }
    const int seg_start = lo;
    hi = n_atoms;
    while (lo < hi) { int mid = (lo + hi) >> 1; if (owner[mid] < g + 1) lo = mid + 1; else hi = mid; }
    const int seg_end = lo;

    float acc[8];
    #pragma unroll
    for (int j = 0; j < 8; ++j) acc[j] = 0.f;
    float ps = 0.f;

    __syncthreads();

    for (int base = seg_start; base < seg_end; base += CHUNK) {
        const int na = min(CHUNK, seg_end - base);
        {
            const int nf4 = na * (D / 4);
            const float4* src = (const float4*)(atom_feas + (size_t)base * D);
            float4* dst = (float4*)fea_lds;
            for (int i = tid; i < nf4; i += 256) dst[i] = src[i];
        }
        __syncthreads();

        for (int pi = tid; pi < na * H; pi += 256) {
            const int aa = pi >> 5;
            const int hh = pi & 31;
            const float* fr = fea_lds + aa * D;
            float wvl = bk_lds[hh];
            #pragma unroll
            for (int k = 0; k < D; k += 4) {
                float4 f = *(const float4*)(fr + k);
                wvl += f.x * wk_lds[(k + 0) * H + hh];
                wvl += f.y * wk_lds[(k + 1) * H + hh];
                wvl += f.z * wk_lds[(k + 2) * H + hh];
                wvl += f.w * wk_lds[(k + 3) * H + hh];
            }
            w_lds[pi] = __expf(wvl);
        }
        __syncthreads();

        for (int aa = 0; aa < na; ++aa) {
            const float p = w_lds[aa * H + h];
            ps += p;
            const float* f = fea_lds + aa * D + grp * 8;
            #pragma unroll
            for (int j = 0; j < 8; ++j) acc[j] += f[j] * p;
        }
        __syncthreads();
    }

    const float inv = (ps > 0.f) ? 1.0f / ps : 0.f;
    float* og = out + (size_t)g * (D * H);
    #pragma unroll
    for (int j = 0; j < 8; ++j) og[(grp * 8 + j) * H + h] = acc[j] * inv;
}

extern "C" void kernel_launch(void* const* d_in, const int* in_sizes, int n_in,
                              void* d_out, int out_size, void* d_ws, size_t ws_size,
                              hipStream_t stream) {
    const float* atom_feas = (const float*)d_in[0];
    const float* Wk        = (const float*)d_in[1];
    const float* bk        = (const float*)d_in[2];
    // d_in[3] = atomic_numbers (unused by the reference)
    const int*   owner     = (const int*)d_in[4];
    const int n_atoms = in_sizes[4];
    float* out = (float*)d_out;

    const size_t bounds_bytes = 16384;
    const size_t f16_bytes = (size_t)n_atoms * D * 2;

    if (ws_size >= bounds_bytes + f16_bytes) {
        int*   bounds = (int*)d_ws;
        uint2* f16fea = (uint2*)((char*)d_ws + bounds_bytes);

        const int nf4 = n_atoms * (D / 4);
        convert_bounds_kernel<<<(nf4 + 255) / 256, 256, 0, stream>>>(
            atom_feas, owner, f16fea, bounds, n_atoms);
        crystal_kernel<<<NC, 64, 0, stream>>>(
            (const uint4*)f16fea, Wk, bk, bounds, out);
    } else {
        fused_kernel<<<NC, 256, 0, stream>>>(atom_feas, Wk, bk, owner, out, n_atoms);
    }
}